// Round 5
// baseline (689.102 us; speedup 1.0000x reference)
//
#include <hip/hip_runtime.h>
#include <hip/hip_cooperative_groups.h>
#include <cmath>

namespace cg = cooperative_groups;

#define BB 16
#define NN 1024
#define MM 1024
#define ITERS 10

static constexpr float TAU     = 0.05f;
static constexpr float INV_TAU = 1.0f / TAU;
static constexpr float LR      = 0.5f;
static constexpr float B1f     = 0.9f;
static constexpr float B2f     = 0.999f;
static constexpr float EPSA    = 1e-8f;
// Clamp the exp ARGUMENT (survives -ffinite-math-only; result-clamp gets folded).
static constexpr float EXP_CAP = 88.0f;

// dynamic LDS: buf[16 waves][64 lanes][17 pad] + wgmax[1024] + vsh[1024]
#define BUF_FLOATS (16 * 64 * 17)
#define LDS_FLOATS (BUF_FLOATS + MM + MM)

// Persistent cooperative kernel: entire K tile lives in VGPRs.
// wg (b,g) owns rows [g*64, g*64+64) of batch b; wave owns 4 rows; lane owns
// 16 consecutive cols. u-Adam state: registers, lane-replicated. v-Adam state:
// thread owns column tid of batch b, replicated across the batch's 16 wgs
// (identical deterministic inputs -> identical trajectories).
__global__ void __launch_bounds__(1024, 4)
sinkhorn_persist(const float* __restrict__ la, const float* __restrict__ log_a,
                 const float* __restrict__ log_b, float* __restrict__ out,
                 float2* __restrict__ part /* [2][BB][16][MM] double-buffered */)
{
    cg::grid_group grid = cg::this_grid();
    extern __shared__ float lds[];
    float* buf   = lds;                 // [wave][lane][17]
    float* wgmax = lds + BUF_FLOATS;    // [1024] per-wg column max
    float* vsh   = wgmax + MM;          // [1024] current v for this batch

    const int b    = blockIdx.x >> 4;
    const int g    = blockIdx.x & 15;
    const int tid  = threadIdx.x;
    const int wave = tid >> 6;
    const int lane = tid & 63;
    const int grow = (g << 6) | (wave << 2);   // first of 4 rows (within batch)
    const int col0 = lane << 4;                // first of 16 cols

    // ---- load K tile into registers, pre-scaled by 1/TAU ----
    const float* kbase = la + ((size_t)b * NN + grow) * MM + col0;
    float krf[4][16];
#pragma unroll
    for (int r = 0; r < 4; ++r)
#pragma unroll
        for (int q = 0; q < 4; ++q) {
            float4 t = *(const float4*)(kbase + (size_t)r * MM + 4 * q);
            krf[r][4*q+0] = t.x * INV_TAU;
            krf[r][4*q+1] = t.y * INV_TAU;
            krf[r][4*q+2] = t.z * INV_TAU;
            krf[r][4*q+3] = t.w * INV_TAU;
        }

    float u[4] = {0,0,0,0}, mu[4] = {0,0,0,0}, vu[4] = {0,0,0,0};
    float lam[4];
#pragma unroll
    for (int r = 0; r < 4; ++r) lam[r] = log_a[b * NN + grow + r];
    float vcol = 0.f, mvv = 0.f, vvv = 0.f;
    const float lbm = log_b[b * MM + tid];

    vsh[tid] = 0.f;
    float* myb = buf + tid * 17;
    __syncthreads();

    float b1p = 1.f, b2p = 1.f;
    for (int it = 0; it < ITERS; ++it) {
        b1p *= B1f; b2p *= B2f;
        const float bc1 = 1.f - b1p, bc2 = 1.f - b2p;

        // ========== row pass: lse over cols of (K + v_{t-1}) -> Adam u ==========
#pragma unroll
        for (int r = 0; r < 4; ++r) {
            float mx = -3.0e38f;
#pragma unroll
            for (int q = 0; q < 4; ++q) {
                const float4 vq = *(const float4*)(vsh + col0 + 4*q);
                mx = fmaxf(mx, fmaxf(fmaxf(krf[r][4*q+0] + vq.x, krf[r][4*q+1] + vq.y),
                                     fmaxf(krf[r][4*q+2] + vq.z, krf[r][4*q+3] + vq.w)));
            }
#pragma unroll
            for (int off = 32; off; off >>= 1)
                mx = fmaxf(mx, __shfl_xor(mx, off, 64));
            float s = 0.f;
#pragma unroll
            for (int q = 0; q < 4; ++q) {
                const float4 vq = *(const float4*)(vsh + col0 + 4*q);
                s += __expf(krf[r][4*q+0] + vq.x - mx);
                s += __expf(krf[r][4*q+1] + vq.y - mx);
                s += __expf(krf[r][4*q+2] + vq.z - mx);
                s += __expf(krf[r][4*q+3] + vq.w - mx);
            }
#pragma unroll
            for (int off = 32; off; off >>= 1)
                s += __shfl_xor(s, off, 64);
            const float lse = mx + __logf(s);   // all lanes hold lse (butterfly)
            const float gu  = (lam[r] - lse) - u[r];
            mu[r] = B1f * mu[r] + (1.f - B1f) * gu;
            vu[r] = B2f * vu[r] + (1.f - B2f) * gu * gu;
            u[r] += LR * (mu[r] / bc1) / (sqrtf(vu[r] / bc2) + EPSA);
        }

        // ========== col pass A: per-thread 4-row max/col -> wg col max ==========
#pragma unroll
        for (int j = 0; j < 16; ++j)
            myb[j] = fmaxf(fmaxf(krf[0][j] + u[0], krf[1][j] + u[1]),
                           fmaxf(krf[2][j] + u[2], krf[3][j] + u[3]));
        __syncthreads();
        float Mcol;
        {   // thread tid merges the 16 wave-maxes of column tid
            const float* p = buf + (tid >> 4) * 17 + (tid & 15);
            float M = p[0];
#pragma unroll
            for (int wv = 1; wv < 16; ++wv) M = fmaxf(M, p[wv * 64 * 17]);
            Mcol = M;
            wgmax[tid] = M;
        }
        __syncthreads();

        // ========== col pass B: exp-sums vs wg max ==========
#pragma unroll
        for (int q = 0; q < 4; ++q) {
            const float4 wq = *(const float4*)(wgmax + col0 + 4*q);
            const float wm[4] = {wq.x, wq.y, wq.z, wq.w};
#pragma unroll
            for (int k = 0; k < 4; ++k) {
                const int j = 4*q + k;
                myb[j] = __expf(krf[0][j] + u[0] - wm[k])
                       + __expf(krf[1][j] + u[1] - wm[k])
                       + __expf(krf[2][j] + u[2] - wm[k])
                       + __expf(krf[3][j] + u[3] - wm[k]);
            }
        }
        __syncthreads();
        {   // merge 16 wave-sums (same max -> plain add), write wg partial
            const float* p = buf + (tid >> 4) * 17 + (tid & 15);
            float S = p[0];
#pragma unroll
            for (int wv = 1; wv < 16; ++wv) S += p[wv * 64 * 17];
            part[(((size_t)(it & 1) * BB + b) * 16 + g) * MM + tid] = make_float2(Mcol, S);
        }

        grid.sync();   // partials from all 16 slabs of each batch now visible

        // ========== v update: merge 16 slab partials, Adam v ==========
        {
            const float2* pp = part + (((size_t)(it & 1) * BB + b) * 16) * MM + tid;
            float2 pg[16];
#pragma unroll
            for (int gp = 0; gp < 16; ++gp) pg[gp] = pp[(size_t)gp * MM];
            float M = pg[0].x;
#pragma unroll
            for (int gp = 1; gp < 16; ++gp) M = fmaxf(M, pg[gp].x);
            float S = 0.f;
#pragma unroll
            for (int gp = 0; gp < 16; ++gp) S += pg[gp].y * __expf(pg[gp].x - M);
            const float lse = M + __logf(S);
            const float gv  = (lbm - lse) - vcol;
            mvv = B1f * mvv + (1.f - B1f) * gv;
            vvv = B2f * vvv + (1.f - B2f) * gv * gv;
            vcol += LR * (mvv / bc1) / (sqrtf(vvv / bc2) + EPSA);
            vsh[tid] = vcol;
        }
        __syncthreads();   // vsh ready for next row pass / finalize
    }

    // ========== finalize: out = exp(K + u + v), arg-clamped ==========
    float* obase = out + ((size_t)b * NN + grow) * MM + col0;
#pragma unroll
    for (int r = 0; r < 4; ++r) {
#pragma unroll
        for (int q = 0; q < 4; ++q) {
            const float4 vq = *(const float4*)(vsh + col0 + 4*q);
            float4 o;
            o.x = __expf(fminf(krf[r][4*q+0] + u[r] + vq.x, EXP_CAP));
            o.y = __expf(fminf(krf[r][4*q+1] + u[r] + vq.y, EXP_CAP));
            o.z = __expf(fminf(krf[r][4*q+2] + u[r] + vq.z, EXP_CAP));
            o.w = __expf(fminf(krf[r][4*q+3] + u[r] + vq.w, EXP_CAP));
            *(float4*)(obase + (size_t)r * MM + 4*q) = o;
        }
    }
}

extern "C" void kernel_launch(void* const* d_in, const int* in_sizes, int n_in,
                              void* d_out, int out_size, void* d_ws, size_t ws_size,
                              hipStream_t stream) {
    const float* la    = (const float*)d_in[0];
    const float* log_a = (const float*)d_in[1];
    const float* log_b = (const float*)d_in[2];
    float*  out  = (float*)d_out;
    float2* part = (float2*)d_ws;   // 2*16*16*1024 float2 = 4 MB

    // allow >64 KB dynamic LDS (77,824 B); host-side attr set, capture-safe
    (void)hipFuncSetAttribute((const void*)sinkhorn_persist,
                              hipFuncAttributeMaxDynamicSharedMemorySize,
                              LDS_FLOATS * 4);

    void* args[] = {(void*)&la, (void*)&log_a, (void*)&log_b, (void*)&out, (void*)&part};
    (void)hipLaunchCooperativeKernel((const void*)sinkhorn_persist,
                                     dim3(BB * 16), dim3(1024),
                                     args, LDS_FLOATS * 4, stream);
}

// Round 6
// 426.282 us; speedup vs baseline: 1.6165x; 1.6165x over previous
//
#include <hip/hip_runtime.h>
#include <cmath>

#define BB 16
#define NN 1024
#define MM 1024
#define RPB 8              // rows per block in fused kernel
#define NSLAB (NN / RPB)   // 128 slabs per batch

static constexpr float INV_TAU = 20.0f;   // 1/0.05
static constexpr float LR   = 0.5f;
static constexpr float B1f  = 0.9f;
static constexpr float B2f  = 0.999f;
static constexpr float EPSA = 1e-8f;
// Clamp the exp ARGUMENT (survives -ffinite-math-only; result-clamp is folded
// away under fast-math — root cause of the R0-R2 inf->NaN failures).
static constexpr float EXP_CAP = 88.0f;

// d_ws layout (floats): u v mu vu mv vv, then part[BB][NSLAB][MM] as float2
#define OFF_U   0
#define OFF_V   16384
#define OFF_MU  32768
#define OFF_VU  49152
#define OFF_MV  65536
#define OFF_VV  81920
#define OFF_PART 98304     // float2 region: 16*128*1024*8 B = 16 MB

// ---- zero Adam state ----
__global__ void init_state(float* __restrict__ ws) {
    int i = blockIdx.x * 256 + threadIdx.x;   // 384 blocks
    ws[i] = 0.0f;
}

// ---- fused: row lse + Adam-u for an 8-row slab, then column partials ----
// grid (NSLAB, BB), 256 threads. Row pass: wave w handles rows 2w, 2w+1.
// Col pass re-reads the slab (L1/L2-hot, 32 KB) with the fresh u.
__global__ __launch_bounds__(256, 8) void iter_fused(
    const float* __restrict__ la, const float* __restrict__ log_a,
    float* __restrict__ ws, float2* __restrict__ part,
    float bc1, float bc2)
{
    const int slab = blockIdx.x;
    const int b    = blockIdx.y;
    const int row0 = slab * RPB;
    const int tid  = threadIdx.x;
    const int wave = tid >> 6;
    const int lane = tid & 63;
    __shared__ float su[RPB];                 // fresh u for this slab's rows

    const float* vg = ws + OFF_V + b * MM;

    // ===== row pass =====
    for (int rr = 0; rr < 2; ++rr) {
        const int r   = 2 * wave + rr;        // 0..7
        const int row = row0 + r;
        const float* K = la + ((size_t)b * NN + row) * MM;
        float w[16];
        float mx = -3.0e38f;
#pragma unroll
        for (int q = 0; q < 4; ++q) {
            const int c = 4 * lane + 256 * q;               // coalesced float4
            const float4 k4 = *(const float4*)(K + c);
            const float4 v4 = *(const float4*)(vg + c);
            w[4*q+0] = k4.x * INV_TAU + v4.x;
            w[4*q+1] = k4.y * INV_TAU + v4.y;
            w[4*q+2] = k4.z * INV_TAU + v4.z;
            w[4*q+3] = k4.w * INV_TAU + v4.w;
            mx = fmaxf(mx, fmaxf(fmaxf(w[4*q+0], w[4*q+1]),
                                 fmaxf(w[4*q+2], w[4*q+3])));
        }
#pragma unroll
        for (int off = 32; off; off >>= 1)
            mx = fmaxf(mx, __shfl_xor(mx, off, 64));
        float s = 0.f;
#pragma unroll
        for (int j = 0; j < 16; ++j) s += __expf(w[j] - mx);
#pragma unroll
        for (int off = 32; off; off >>= 1)
            s += __shfl_xor(s, off, 64);
        if (lane == 0) {
            const int gi  = b * NN + row;
            const float lse = mx + __logf(s);
            const float uo  = ws[OFF_U + gi];
            const float gu  = (log_a[gi] - lse) - uo;
            const float m_  = B1f * ws[OFF_MU + gi] + (1.f - B1f) * gu;
            const float v_  = B2f * ws[OFF_VU + gi] + (1.f - B2f) * gu * gu;
            ws[OFF_MU + gi] = m_;
            ws[OFF_VU + gi] = v_;
            const float un  = uo + LR * (m_ / bc1) / (sqrtf(v_ / bc2) + EPSA);
            ws[OFF_U + gi]  = un;
            su[r] = un;
        }
    }
    __syncthreads();

    // ===== col pass: thread t owns cols 4t..4t+3, online lse over 8 rows =====
    float uu[RPB];
#pragma unroll
    for (int r = 0; r < RPB; ++r) uu[r] = su[r];
    float M[4] = {-3.0e38f, -3.0e38f, -3.0e38f, -3.0e38f};
    float S[4] = {0.f, 0.f, 0.f, 0.f};
    const float* Kc = la + ((size_t)b * NN + row0) * MM + 4 * tid;
#pragma unroll
    for (int r = 0; r < RPB; ++r) {
        const float4 k4 = *(const float4*)(Kc + (size_t)r * MM);
        float w0 = k4.x * INV_TAU + uu[r];
        float w1 = k4.y * INV_TAU + uu[r];
        float w2 = k4.z * INV_TAU + uu[r];
        float w3 = k4.w * INV_TAU + uu[r];
        float mn;
        mn = fmaxf(M[0], w0); S[0] = S[0] * __expf(M[0] - mn) + __expf(w0 - mn); M[0] = mn;
        mn = fmaxf(M[1], w1); S[1] = S[1] * __expf(M[1] - mn) + __expf(w1 - mn); M[1] = mn;
        mn = fmaxf(M[2], w2); S[2] = S[2] * __expf(M[2] - mn) + __expf(w2 - mn); M[2] = mn;
        mn = fmaxf(M[3], w3); S[3] = S[3] * __expf(M[3] - mn) + __expf(w3 - mn); M[3] = mn;
    }
    float2* p = part + ((size_t)b * NSLAB + slab) * MM + 4 * tid;
    p[0] = make_float2(M[0], S[0]);
    p[1] = make_float2(M[1], S[1]);
    p[2] = make_float2(M[2], S[2]);
    p[3] = make_float2(M[3], S[3]);
}

// ---- combine: merge NSLAB partials per column, Adam-v ----
__global__ __launch_bounds__(256, 8) void combine(
    const float* __restrict__ log_b, float* __restrict__ ws,
    const float2* __restrict__ part, float bc1, float bc2)
{
    const int i = blockIdx.x * 256 + threadIdx.x;   // b*MM + m
    const int b = i >> 10;
    const int m = i & 1023;
    const float2* p = part + (size_t)b * NSLAB * MM + m;
    float M[4] = {-3.0e38f, -3.0e38f, -3.0e38f, -3.0e38f};
    float S[4] = {0.f, 0.f, 0.f, 0.f};
#pragma unroll 4
    for (int g = 0; g < NSLAB; g += 4) {
#pragma unroll
        for (int j = 0; j < 4; ++j) {
            const float2 pr = p[(size_t)(g + j) * MM];
            const float mn = fmaxf(M[j], pr.x);
            S[j] = S[j] * __expf(M[j] - mn) + pr.y * __expf(pr.x - mn);
            M[j] = mn;
        }
    }
    float Mt = fmaxf(fmaxf(M[0], M[1]), fmaxf(M[2], M[3]));
    float St = S[0] * __expf(M[0] - Mt) + S[1] * __expf(M[1] - Mt)
             + S[2] * __expf(M[2] - Mt) + S[3] * __expf(M[3] - Mt);
    const float lse = Mt + __logf(St);
    const float vo  = ws[OFF_V + i];
    const float gv  = (log_b[i] - lse) - vo;
    const float m_  = B1f * ws[OFF_MV + i] + (1.f - B1f) * gv;
    const float v_  = B2f * ws[OFF_VV + i] + (1.f - B2f) * gv * gv;
    ws[OFF_MV + i] = m_;
    ws[OFF_VV + i] = v_;
    ws[OFF_V + i]  = vo + LR * (m_ / bc1) / (sqrtf(v_ / bc2) + EPSA);
}

// ---- finalize: out = exp(K + u + v), arg-clamped ----
__global__ void finalize(const float* __restrict__ la, const float* __restrict__ ws,
                         float* __restrict__ out)
{
    const size_t i4 = (size_t)blockIdx.x * 256 + threadIdx.x;
    const size_t e  = i4 * 4;
    const int row = (int)(e >> 10);        // b*NN + n
    const int b   = row >> 10;
    const int m   = (int)(e & 1023);
    const float uu = ws[OFF_U + row];
    const float4 k4 = ((const float4*)la)[i4];
    const float4 v4 = *(const float4*)(ws + OFF_V + b * MM + m);
    float4 o;
    o.x = __expf(fminf(k4.x * INV_TAU + uu + v4.x, EXP_CAP));
    o.y = __expf(fminf(k4.y * INV_TAU + uu + v4.y, EXP_CAP));
    o.z = __expf(fminf(k4.z * INV_TAU + uu + v4.z, EXP_CAP));
    o.w = __expf(fminf(k4.w * INV_TAU + uu + v4.w, EXP_CAP));
    ((float4*)out)[i4] = o;
}

extern "C" void kernel_launch(void* const* d_in, const int* in_sizes, int n_in,
                              void* d_out, int out_size, void* d_ws, size_t ws_size,
                              hipStream_t stream) {
    const float* la    = (const float*)d_in[0];
    const float* log_a = (const float*)d_in[1];
    const float* log_b = (const float*)d_in[2];
    float*  out  = (float*)d_out;
    float*  ws   = (float*)d_ws;
    float2* part = (float2*)(ws + OFF_PART);

    init_state<<<384, 256, 0, stream>>>(ws);
    for (int t = 1; t <= 10; ++t) {
        const float bc1 = 1.0f - powf(B1f, (float)t);
        const float bc2 = 1.0f - powf(B2f, (float)t);
        iter_fused<<<dim3(NSLAB, BB), 256, 0, stream>>>(la, log_a, ws, part, bc1, bc2);
        combine<<<BB * MM / 256, 256, 0, stream>>>(log_b, ws, part, bc1, bc2);
    }
    finalize<<<16384, 256, 0, stream>>>(la, ws, out);
}

// Round 7
// 340.133 us; speedup vs baseline: 2.0260x; 1.2533x over previous
//
#include <hip/hip_runtime.h>
#include <cmath>

#define BB 16
#define NN 1024
#define MM 1024
#define RPB 8              // rows per block in fused kernel
#define NSLAB (NN / RPB)   // 128 slabs per batch

static constexpr float INV_TAU = 20.0f;   // 1/0.05
static constexpr float LR   = 0.5f;
static constexpr float B1f  = 0.9f;
static constexpr float B2f  = 0.999f;
static constexpr float EPSA = 1e-8f;
// Clamp the exp ARGUMENT (survives -ffinite-math-only; result-clamp is folded
// away under fast-math — root cause of the R0-R2 inf->NaN failures).
static constexpr float EXP_CAP = 88.0f;

// d_ws layout (floats): u v mu vu mv vv, then part[BB][NSLAB][MM] as float2
#define OFF_U   0
#define OFF_V   16384
#define OFF_MU  32768
#define OFF_VU  49152
#define OFF_MV  65536
#define OFF_VV  81920
#define OFF_PART 98304     // float2 region: 16*128*1024*8 B = 16 MB

// ---- zero Adam state ----
__global__ void init_state(float* __restrict__ ws) {
    int i = blockIdx.x * 256 + threadIdx.x;   // 384 blocks
    ws[i] = 0.0f;
}

// ---- fused iteration: ONE K read. Slab lives in 32 VGPRs (4 cols x 8 rows
// per thread). Row lse via wave-butterfly + LDS cross-wave; col partials from
// the same registers with the fresh u. ----
__global__ __launch_bounds__(256, 4) void iter_fused(
    const float* __restrict__ la, const float* __restrict__ log_a,
    float* __restrict__ ws, float2* __restrict__ part,
    float bc1, float bc2)
{
    const int slab = blockIdx.x;
    const int b    = blockIdx.y;
    const int row0 = slab * RPB;
    const int tid  = threadIdx.x;
    const int wave = tid >> 6;
    const int lane = tid & 63;
    __shared__ float redm[4 * RPB];   // [wave][row] partial max
    __shared__ float reds[4 * RPB];   // [wave][row] partial sum
    __shared__ float fin[RPB];        // final row max
    __shared__ float su[RPB];         // fresh u

    // ---- load slab into registers, pre-scaled ----
    const float* Kb = la + ((size_t)b * NN + row0) * MM + 4 * tid;
    float kr[RPB][4];
#pragma unroll
    for (int r = 0; r < RPB; ++r) {
        const float4 k4 = *(const float4*)(Kb + (size_t)r * MM);
        kr[r][0] = k4.x * INV_TAU; kr[r][1] = k4.y * INV_TAU;
        kr[r][2] = k4.z * INV_TAU; kr[r][3] = k4.w * INV_TAU;
    }
    const float4 v4 = *(const float4*)(ws + OFF_V + b * MM + 4 * tid);
    const float vj[4] = {v4.x, v4.y, v4.z, v4.w};

    // ---- row pass: max ----
    float pm[RPB];
#pragma unroll
    for (int r = 0; r < RPB; ++r)
        pm[r] = fmaxf(fmaxf(kr[r][0] + vj[0], kr[r][1] + vj[1]),
                      fmaxf(kr[r][2] + vj[2], kr[r][3] + vj[3]));
#pragma unroll
    for (int off = 32; off; off >>= 1)
#pragma unroll
        for (int r = 0; r < RPB; ++r)
            pm[r] = fmaxf(pm[r], __shfl_xor(pm[r], off, 64));
    if (lane == 0)
#pragma unroll
        for (int r = 0; r < RPB; ++r) redm[wave * RPB + r] = pm[r];
    __syncthreads();
    if (tid < RPB)
        fin[tid] = fmaxf(fmaxf(redm[tid], redm[RPB + tid]),
                         fmaxf(redm[2 * RPB + tid], redm[3 * RPB + tid]));
    __syncthreads();
    float Mr[RPB];
#pragma unroll
    for (int r = 0; r < RPB; ++r) Mr[r] = fin[r];

    // ---- row pass: exp-sum ----
    float ps[RPB];
#pragma unroll
    for (int r = 0; r < RPB; ++r)
        ps[r] = __expf(kr[r][0] + vj[0] - Mr[r]) + __expf(kr[r][1] + vj[1] - Mr[r])
              + __expf(kr[r][2] + vj[2] - Mr[r]) + __expf(kr[r][3] + vj[3] - Mr[r]);
#pragma unroll
    for (int off = 32; off; off >>= 1)
#pragma unroll
        for (int r = 0; r < RPB; ++r)
            ps[r] += __shfl_xor(ps[r], off, 64);
    if (lane == 0)
#pragma unroll
        for (int r = 0; r < RPB; ++r) reds[wave * RPB + r] = ps[r];
    __syncthreads();
    if (tid < RPB) {
        const int r  = tid;
        const int gi = b * NN + row0 + r;
        const float S   = reds[r] + reds[RPB + r] + reds[2 * RPB + r] + reds[3 * RPB + r];
        const float lse = Mr[r] + __logf(S);
        const float uo  = ws[OFF_U + gi];
        const float gu  = (log_a[gi] - lse) - uo;
        const float m_  = B1f * ws[OFF_MU + gi] + (1.f - B1f) * gu;
        const float v_  = B2f * ws[OFF_VU + gi] + (1.f - B2f) * gu * gu;
        ws[OFF_MU + gi] = m_;
        ws[OFF_VU + gi] = v_;
        const float un  = uo + LR * (m_ / bc1) / (sqrtf(v_ / bc2) + EPSA);
        ws[OFF_U + gi]  = un;
        su[r] = un;
    }
    __syncthreads();
    float uu[RPB];
#pragma unroll
    for (int r = 0; r < RPB; ++r) uu[r] = su[r];

    // ---- col partials: exact two-pass over registers ----
    float2 out4[4];
#pragma unroll
    for (int j = 0; j < 4; ++j) {
        float m = kr[0][j] + uu[0];
#pragma unroll
        for (int r = 1; r < RPB; ++r) m = fmaxf(m, kr[r][j] + uu[r]);
        float s = 0.f;
#pragma unroll
        for (int r = 0; r < RPB; ++r) s += __expf(kr[r][j] + uu[r] - m);
        out4[j] = make_float2(m, s);
    }
    float2* p = part + ((size_t)b * NSLAB + slab) * MM + 4 * tid;
    p[0] = out4[0]; p[1] = out4[1]; p[2] = out4[2]; p[3] = out4[3];
}

// ---- combine: 256 blocks; block = 64 columns x 4 slab-quarters ----
__global__ __launch_bounds__(256, 8) void combine(
    const float* __restrict__ log_b, float* __restrict__ ws,
    const float2* __restrict__ part, float bc1, float bc2)
{
    const int b   = blockIdx.x >> 4;
    const int mg  = blockIdx.x & 15;
    const int tid = threadIdx.x;
    const int c   = tid & 63;        // column within 64-group (coalesced)
    const int q   = tid >> 6;        // slab quarter (32 slabs each)
    const int m   = mg * 64 + c;
    __shared__ float2 red[4][64];

    const float2* p = part + ((size_t)b * NSLAB + q * 32) * MM + m;
    float M = -3.0e38f, S = 0.f;
#pragma unroll 8
    for (int s = 0; s < 32; ++s) {
        const float2 pr = p[(size_t)s * MM];
        const float mn = fmaxf(M, pr.x);
        S = S * __expf(M - mn) + pr.y * __expf(pr.x - mn);
        M = mn;
    }
    red[q][c] = make_float2(M, S);
    __syncthreads();
    if (q == 0) {
        const float2 a = red[0][c], bb = red[1][c], cc = red[2][c], d = red[3][c];
        const float Mt = fmaxf(fmaxf(a.x, bb.x), fmaxf(cc.x, d.x));
        const float St = a.y * __expf(a.x - Mt) + bb.y * __expf(bb.x - Mt)
                       + cc.y * __expf(cc.x - Mt) + d.y * __expf(d.x - Mt);
        const int i = b * MM + m;
        const float lse = Mt + __logf(St);
        const float vo  = ws[OFF_V + i];
        const float gv  = (log_b[i] - lse) - vo;
        const float m_  = B1f * ws[OFF_MV + i] + (1.f - B1f) * gv;
        const float v_  = B2f * ws[OFF_VV + i] + (1.f - B2f) * gv * gv;
        ws[OFF_MV + i] = m_;
        ws[OFF_VV + i] = v_;
        ws[OFF_V + i]  = vo + LR * (m_ / bc1) / (sqrtf(v_ / bc2) + EPSA);
    }
}

// ---- finalize: out = exp(K + u + v), arg-clamped ----
__global__ void finalize(const float* __restrict__ la, const float* __restrict__ ws,
                         float* __restrict__ out)
{
    const size_t i4 = (size_t)blockIdx.x * 256 + threadIdx.x;
    const size_t e  = i4 * 4;
    const int row = (int)(e >> 10);        // b*NN + n
    const int b   = row >> 10;
    const int m   = (int)(e & 1023);
    const float uu = ws[OFF_U + row];
    const float4 k4 = ((const float4*)la)[i4];
    const float4 v4 = *(const float4*)(ws + OFF_V + b * MM + m);
    float4 o;
    o.x = __expf(fminf(k4.x * INV_TAU + uu + v4.x, EXP_CAP));
    o.y = __expf(fminf(k4.y * INV_TAU + uu + v4.y, EXP_CAP));
    o.z = __expf(fminf(k4.z * INV_TAU + uu + v4.z, EXP_CAP));
    o.w = __expf(fminf(k4.w * INV_TAU + uu + v4.w, EXP_CAP));
    ((float4*)out)[i4] = o;
}

extern "C" void kernel_launch(void* const* d_in, const int* in_sizes, int n_in,
                              void* d_out, int out_size, void* d_ws, size_t ws_size,
                              hipStream_t stream) {
    const float* la    = (const float*)d_in[0];
    const float* log_a = (const float*)d_in[1];
    const float* log_b = (const float*)d_in[2];
    float*  out  = (float*)d_out;
    float*  ws   = (float*)d_ws;
    float2* part = (float2*)(ws + OFF_PART);

    init_state<<<384, 256, 0, stream>>>(ws);
    for (int t = 1; t <= 10; ++t) {
        const float bc1 = 1.0f - powf(B1f, (float)t);
        const float bc2 = 1.0f - powf(B2f, (float)t);
        iter_fused<<<dim3(NSLAB, BB), 256, 0, stream>>>(la, log_a, ws, part, bc1, bc2);
        combine<<<BB * MM / 256, 256, 0, stream>>>(log_b, ws, part, bc1, bc2);
    }
    finalize<<<16384, 256, 0, stream>>>(la, ws, out);
}